// Round 2
// baseline (111.764 us; speedup 1.0000x reference)
//
#include <hip/hip_runtime.h>

#define K_ITERS 20
#define MU_CONST 0.05f
#define BN 128
#define NB_PER_BLOCK 8
#define NBLOCKS 512

typedef const __attribute__((address_space(1))) void* gas_ptr;
typedef __attribute__((address_space(3))) void* las_ptr;

// Persistent: 512 blocks x 128 threads (2 blocks/CU, LDS-capped).
// Thread t owns rows r=t>>1 and r+64, cols [64h, 64h+64), w in 32 float4 regs.
// Next batch's w prefetched into lds_w via global_load_lds during compute.
__global__ __launch_bounds__(128, 1) void nag_kernel(
    const float* __restrict__ w,
    const float* __restrict__ bvec,
    const float* __restrict__ s_ptr,
    float* __restrict__ out,
    int B)
{
    __shared__ __align__(16) float lds_w[BN * BN];   // 64 KiB staging
    __shared__ __align__(16) float y_lds[BN];        // current y

    const int t    = threadIdx.x;     // 0..127
    const int lane = t & 63;
    const int wv   = t >> 6;          // wave 0/1
    const int r    = t >> 1;          // 0..63
    const int h    = t & 1;           // column half
    const int sw   = r & 7;           // read-side swizzle key

    const float s    = *s_ptr;
    const float sqms = sqrtf(MU_CONST * s);
    const float alpha = (1.0f - sqms) / (1.0f + sqms);
    const float ap1   = 1.0f + alpha;

    const int base = blockIdx.x * NB_PER_BLOCK;
    if (base >= B) return;
    const int nb = (B - base < NB_PER_BLOCK) ? (B - base) : NB_PER_BLOCK;

    // Async stage of one batch's 128x128 w into lds_w.
    // LDS write is linear (wave-uniform base + lane*16); the XOR swizzle
    // (c4 ^= rho&7) is applied on the per-lane GLOBAL source address so the
    // strided read-back below is bank-conflict-free (both-sides rule).
    auto stage = [&](int nbatch) {
        const float* wb = w + (size_t)nbatch * (BN * BN);
#pragma unroll
        for (int k = 0; k < 32; ++k) {
            const int inst = wv * 32 + k;            // 64 float4 per inst
            const int rho  = inst * 2 + (lane >> 5); // row this lane feeds
            const int c4   = lane & 31;              // float4 col (linear LDS)
            const int G    = rho * 32 + (c4 ^ (rho & 7)); // swizzled source
            const float* src = wb + (size_t)G * 4;
            float* dst = lds_w + inst * 256;         // wave-uniform LDS base
            __builtin_amdgcn_global_load_lds((gas_ptr)src, (las_ptr)dst, 16, 0, 0);
        }
    };

    float4 wA[16], wB[16];
    const float4* lw4 = (const float4*)lds_w;

    // LDS (staged, swizzled) -> registers; also zero y for the new batch.
    auto copy_regs = [&]() {
#pragma unroll
        for (int j = 0; j < 16; ++j) {
            const int c4 = h * 16 + j;
            wA[j] = lw4[r * 32 + (c4 ^ sw)];
            wB[j] = lw4[(r + 64) * 32 + (c4 ^ sw)];
        }
        if (h == 0) { y_lds[r] = 0.0f; y_lds[r + 64] = 0.0f; }
    };

    // ---- prologue: stage batch 0, wait, copy to regs ----
    stage(base);
    asm volatile("s_waitcnt vmcnt(0)" ::: "memory");
    __builtin_amdgcn_sched_barrier(0);
    __builtin_amdgcn_s_barrier();
    asm volatile("" ::: "memory");
    copy_regs();
    asm volatile("s_waitcnt lgkmcnt(0)" ::: "memory");
    __builtin_amdgcn_sched_barrier(0);
    __builtin_amdgcn_s_barrier();
    asm volatile("" ::: "memory");

    for (int bi = 0; bi < nb; ++bi) {
        const int batch = base + bi;

        // b loads issued BEFORE the prefetch so their waitcnt doesn't drain it
        const float b0 = bvec[(size_t)batch * BN + r];
        const float b1 = bvec[(size_t)batch * BN + r + 64];

        if (bi + 1 < nb) stage(batch + 1);   // overlaps with compute below

        float x0 = 0.f, x1 = 0.f, ys0 = 0.f, ys1 = 0.f;

        for (int it = 0; it < K_ITERS; ++it) {
            const float4* y4 = (const float4*)y_lds + h * 16;
            float p0 = 0.f, p1 = 0.f;
#pragma unroll
            for (int j = 0; j < 16; ++j) {
                float4 yv = y4[j];
                p0 += wA[j].x * yv.x; p0 += wA[j].y * yv.y;
                p0 += wA[j].z * yv.z; p0 += wA[j].w * yv.w;
                p1 += wB[j].x * yv.x; p1 += wB[j].y * yv.y;
                p1 += wB[j].z * yv.z; p1 += wB[j].w * yv.w;
            }
            const float d0 = p0 + __shfl_xor(p0, 1);
            const float d1 = p1 + __shfl_xor(p1, 1);
            const float xn0 = ys0 - s * (d0 - b0);
            const float xn1 = ys1 - s * (d1 - b1);
            ys0 = ap1 * xn0 - alpha * x0;
            ys1 = ap1 * xn1 - alpha * x1;
            x0 = xn0; x1 = xn1;

            // Raw barriers: must NOT drain vmcnt (prefetch stays in flight).
            asm volatile("" ::: "memory");
            __builtin_amdgcn_s_barrier();          // all y reads done
            asm volatile("" ::: "memory");
            if (h == 0) { y_lds[r] = ys0; y_lds[r + 64] = ys1; }
            asm volatile("s_waitcnt lgkmcnt(0)" ::: "memory");
            __builtin_amdgcn_sched_barrier(0);
            __builtin_amdgcn_s_barrier();          // new y visible
            asm volatile("" ::: "memory");
        }

        // outputs: x then y, each B*BN flat; both lanes hold both rows' state
        {
            const size_t ob = (size_t)batch * BN;
            const size_t oy = (size_t)B * BN;
            if (h == 0) { out[ob + r] = x0;        out[ob + r + 64] = x1; }
            else        { out[oy + ob + r] = ys0;  out[oy + ob + r + 64] = ys1; }
        }

        // batch switch: drain prefetch ONCE, copy staged w to regs
        if (bi + 1 < nb) {
            asm volatile("s_waitcnt vmcnt(0)" ::: "memory");
            __builtin_amdgcn_sched_barrier(0);
            __builtin_amdgcn_s_barrier();          // staged tile visible
            asm volatile("" ::: "memory");
            copy_regs();
            asm volatile("s_waitcnt lgkmcnt(0)" ::: "memory");
            __builtin_amdgcn_sched_barrier(0);
            __builtin_amdgcn_s_barrier();          // copies done -> lds_w free
            asm volatile("" ::: "memory");
        }
    }
}

extern "C" void kernel_launch(void* const* d_in, const int* in_sizes, int n_in,
                              void* d_out, int out_size, void* d_ws, size_t ws_size,
                              hipStream_t stream) {
    const float* w = (const float*)d_in[0];
    const float* b = (const float*)d_in[1];
    const float* s = (const float*)d_in[2];
    float* out = (float*)d_out;
    const int B = in_sizes[1] / BN;    // 4096
    nag_kernel<<<dim3(NBLOCKS), dim3(128), 0, stream>>>(w, b, s, out, B);
}